// Round 1
// baseline (559.419 us; speedup 1.0000x reference)
//
#include <hip/hip_runtime.h>
#include <hip/hip_bf16.h>

// Problem constants
#define BSZ 4
#define SEQ 2048
#define NH  16
#define DH  64
#define TOK (BSZ*SEQ)          // 8192 tokens
#define PROJC (NH*DH)          // 1024

typedef __bf16 bf16x8 __attribute__((ext_vector_type(8)));
typedef float  f32x4  __attribute__((ext_vector_type(4)));
typedef unsigned int uint4v __attribute__((ext_vector_type(4)));

__device__ inline unsigned short f2bf(float f) {
    unsigned int u = __builtin_bit_cast(unsigned int, f);
    unsigned int r = (u + 0x7FFFu + ((u >> 16) & 1u)) >> 16;
    return (unsigned short)r;
}

__device__ inline bf16x8 ld8(const unsigned short* p) {
    return __builtin_bit_cast(bf16x8, *reinterpret_cast<const uint4v*>(p));
}

// ---------------- prep: f32 -> bf16 copies of q_origin / k_origin ----------
__global__ __launch_bounds__(256) void conv_kernel(const float* __restrict__ q,
                                                   const float* __restrict__ k,
                                                   unsigned short* __restrict__ qbf,
                                                   unsigned short* __restrict__ kbf) {
    int idx = blockIdx.x * 256 + threadIdx.x;       // 0 .. 524287
    if (blockIdx.y == 0) qbf[idx] = f2bf(q[idx]);
    else                 kbf[idx] = f2bf(k[idx]);
}

// ---------------- prep: W [64][cols] f32 -> WT [cols][64] bf16 -------------
__global__ __launch_bounds__(256) void wt_kernel(const float* __restrict__ W,
                                                 unsigned short* __restrict__ WT,
                                                 int cols) {
    int idx = blockIdx.x * 256 + threadIdx.x;
    int n = 64 * cols;
    if (idx >= n) return;
    int c = idx % cols, k = idx / cols;             // coalesced read over c
    WT[c * 64 + k] = f2bf(W[k * cols + c]);
}

// ---------------- projections: tokens x 64 @ 64 x 1024 ---------------------
// z=0: Q = qbf @ Wq  -> Q[bh][q][64]
// z=1: K = kbf @ Wk  -> K[bh][k][64]
// z=2: V = kbf @ Wv  -> Vt[bh][64][k]   (transposed for PV B-fragments)
__global__ __launch_bounds__(256) void proj_kernel(const unsigned short* __restrict__ qbf,
                                                   const unsigned short* __restrict__ kbf,
                                                   const unsigned short* __restrict__ WqT,
                                                   const unsigned short* __restrict__ WkT,
                                                   const unsigned short* __restrict__ WvT,
                                                   unsigned short* __restrict__ Qo,
                                                   unsigned short* __restrict__ Ko,
                                                   unsigned short* __restrict__ Vto) {
    int z = blockIdx.z;
    const unsigned short* A  = (z == 0) ? qbf : kbf;
    const unsigned short* WT = (z == 0) ? WqT : (z == 1) ? WkT : WvT;
    int tid = threadIdx.x, w = tid >> 6, lane = tid & 63;
    int l15 = lane & 15, l4 = lane >> 4;
    int r0 = blockIdx.x * 64 + w * 16;
    int c0 = blockIdx.y * 64;

    const unsigned short* ap = A + (r0 + l15) * 64 + l4 * 8;
    bf16x8 a0 = ld8(ap), a1 = ld8(ap + 32);

    for (int ct = 0; ct < 4; ++ct) {
        const unsigned short* wp = WT + (c0 + ct * 16 + l15) * 64 + l4 * 8;
        bf16x8 b0 = ld8(wp), b1 = ld8(wp + 32);
        f32x4 acc = {0.f, 0.f, 0.f, 0.f};
        acc = __builtin_amdgcn_mfma_f32_16x16x32_bf16(a0, b0, acc, 0, 0, 0);
        acc = __builtin_amdgcn_mfma_f32_16x16x32_bf16(a1, b1, acc, 0, 0, 0);
        for (int r = 0; r < 4; ++r) {
            int row = r0 + l4 * 4 + r;
            int col = c0 + ct * 16 + l15;
            int b = row >> 11, q = row & 2047;
            int h = col >> 6,  dd = col & 63;
            unsigned short val = f2bf(acc[r]);
            size_t bh = (size_t)(b * NH + h);
            if (z == 0)      Qo [(bh * SEQ + q) * 64 + dd] = val;
            else if (z == 1) Ko [(bh * SEQ + q) * 64 + dd] = val;
            else             Vto[(bh * 64 + dd) * SEQ + q] = val;
        }
    }
}

// ---------------- flash attention with boolean mask ------------------------
// grid (32 qtiles, 64 bh), 256 threads = 4 waves, wave owns 16 q rows.
__global__ __launch_bounds__(256) void attn_kernel(const unsigned short* __restrict__ Q,
                                                   const unsigned short* __restrict__ K,
                                                   const unsigned short* __restrict__ Vt,
                                                   const int* __restrict__ mask,
                                                   unsigned short* __restrict__ O) {
    __shared__ __align__(16) unsigned short Pl[4][16][72];   // per-wave, +8 pad
    int tid = threadIdx.x, w = tid >> 6, lane = tid & 63;
    int l15 = lane & 15, l4 = lane >> 4;
    int bh = blockIdx.y, b = bh >> 4;
    int qbase = blockIdx.x * 64 + w * 16;

    const unsigned short* Qh = Q  + (size_t)bh * SEQ * 64;
    const unsigned short* Kh = K  + (size_t)bh * SEQ * 64;
    const unsigned short* Vh = Vt + (size_t)bh * 64 * SEQ;
    const int* mb = mask + (size_t)b * SEQ * SEQ + (size_t)qbase * SEQ;

    const unsigned short* qp = Qh + (qbase + l15) * 64 + l4 * 8;
    bf16x8 qf0 = ld8(qp), qf1 = ld8(qp + 32);

    f32x4 o[4];
    for (int i = 0; i < 4; ++i) o[i] = f32x4{0.f, 0.f, 0.f, 0.f};
    float m[4], ell[4];
    for (int r = 0; r < 4; ++r) { m[r] = -1e30f; ell[r] = 0.f; }
    const float C = 0.125f * 1.44269504088896f;   // scale * log2(e)

    for (int kb = 0; kb < SEQ; kb += 64) {
        // ---- S = Q K^T for 4 tiles of 16 k-cols
        f32x4 s[4];
        for (int t = 0; t < 4; ++t) {
            const unsigned short* kp = Kh + (kb + t * 16 + l15) * 64 + l4 * 8;
            bf16x8 k0 = ld8(kp), k1 = ld8(kp + 32);
            f32x4 z = {0.f, 0.f, 0.f, 0.f};
            z = __builtin_amdgcn_mfma_f32_16x16x32_bf16(qf0, k0, z, 0, 0, 0);
            z = __builtin_amdgcn_mfma_f32_16x16x32_bf16(qf1, k1, z, 0, 0, 0);
            s[t] = z;
        }
        // ---- mask (True -> -inf), mask is per (b,q,k), int32 on device
        for (int t = 0; t < 4; ++t)
            for (int r = 0; r < 4; ++r) {
                int mv = mb[(l4 * 4 + r) * SEQ + kb + t * 16 + l15];
                if (mv) s[t][r] = -1e30f;
            }
        // ---- row max (over 4 tiles in-lane, then 16 lanes of the l4 group)
        float pm[4];
        for (int r = 0; r < 4; ++r)
            pm[r] = fmaxf(fmaxf(s[0][r], s[1][r]), fmaxf(s[2][r], s[3][r]));
        for (int off = 8; off >= 1; off >>= 1)
            for (int r = 0; r < 4; ++r)
                pm[r] = fmaxf(pm[r], __shfl_xor(pm[r], off, 64));
        // ---- online softmax update
        float corr[4], ps[4];
        for (int r = 0; r < 4; ++r) {
            float mn = fmaxf(m[r], pm[r]);
            corr[r] = __builtin_exp2f((m[r] - mn) * C);
            m[r] = mn;
            ps[r] = 0.f;
        }
        for (int t = 0; t < 4; ++t)
            for (int r = 0; r < 4; ++r) {
                float p = __builtin_exp2f((s[t][r] - m[r]) * C);
                s[t][r] = p;
                ps[r] += p;
            }
        for (int off = 8; off >= 1; off >>= 1)
            for (int r = 0; r < 4; ++r)
                ps[r] += __shfl_xor(ps[r], off, 64);
        for (int r = 0; r < 4; ++r) ell[r] = ell[r] * corr[r] + ps[r];
        for (int dt = 0; dt < 4; ++dt)
            for (int r = 0; r < 4; ++r) o[dt][r] *= corr[r];
        // ---- P (D-frag layout) -> LDS -> A-frag layout
        for (int t = 0; t < 4; ++t)
            for (int r = 0; r < 4; ++r)
                Pl[w][l4 * 4 + r][t * 16 + l15] = f2bf(s[t][r]);
        bf16x8 pa0 = ld8(&Pl[w][l15][l4 * 8]);
        bf16x8 pa1 = ld8(&Pl[w][l15][l4 * 8 + 32]);
        // ---- O += P V
        for (int dt = 0; dt < 4; ++dt) {
            const unsigned short* vp = Vh + (dt * 16 + l15) * SEQ + kb + l4 * 8;
            bf16x8 v0 = ld8(vp), v1 = ld8(vp + 32);
            o[dt] = __builtin_amdgcn_mfma_f32_16x16x32_bf16(pa0, v0, o[dt], 0, 0, 0);
            o[dt] = __builtin_amdgcn_mfma_f32_16x16x32_bf16(pa1, v1, o[dt], 0, 0, 0);
        }
    }
    // ---- normalize + store O[bh][q][64]; fully-masked rows -> 0 (nan_to_num)
    float rcp[4];
    for (int r = 0; r < 4; ++r)
        rcp[r] = (m[r] <= -1e29f) ? 0.f : 1.f / ell[r];
    for (int dt = 0; dt < 4; ++dt)
        for (int r = 0; r < 4; ++r)
            O[((size_t)bh * SEQ + qbase + l4 * 4 + r) * 64 + dt * 16 + l15] =
                f2bf(o[dt][r] * rcp[r]);
}

// ---------------- FC + tanh: rows ordered (b, q, h) ------------------------
__global__ __launch_bounds__(256) void fc_kernel(const unsigned short* __restrict__ O,
                                                 const unsigned short* __restrict__ WfcT,
                                                 const float* __restrict__ bfc,
                                                 float* __restrict__ out) {
    int tid = threadIdx.x, w = tid >> 6, lane = tid & 63;
    int l15 = lane & 15, l4 = lane >> 4;
    int r0 = blockIdx.x * 64 + w * 16;

    // A-frag row = r0 + l15, decompose (b, q, h) with h fastest
    int row = r0 + l15;
    int h = row & 15, t_ = row >> 4;
    int q = t_ & 2047, b = t_ >> 11;
    const unsigned short* op = O + (((size_t)(b * NH + h)) * SEQ + q) * 64 + l4 * 8;
    bf16x8 a0 = ld8(op), a1 = ld8(op + 32);

    for (int ct = 0; ct < 4; ++ct) {
        const unsigned short* wp = WfcT + (ct * 16 + l15) * 64 + l4 * 8;
        bf16x8 b0 = ld8(wp), b1 = ld8(wp + 32);
        f32x4 acc = {0.f, 0.f, 0.f, 0.f};
        acc = __builtin_amdgcn_mfma_f32_16x16x32_bf16(a0, b0, acc, 0, 0, 0);
        acc = __builtin_amdgcn_mfma_f32_16x16x32_bf16(a1, b1, acc, 0, 0, 0);
        float bias = bfc[ct * 16 + l15];
        for (int r = 0; r < 4; ++r)
            out[(size_t)(r0 + l4 * 4 + r) * 64 + ct * 16 + l15] =
                tanhf(acc[r] + bias);
    }
}

extern "C" void kernel_launch(void* const* d_in, const int* in_sizes, int n_in,
                              void* d_out, int out_size, void* d_ws, size_t ws_size,
                              hipStream_t stream) {
    const float* q_origin = (const float*)d_in[0];
    const float* k_origin = (const float*)d_in[1];
    const int*   mask     = (const int*)d_in[2];
    const float* Wq       = (const float*)d_in[3];
    const float* Wk       = (const float*)d_in[4];
    const float* Wv       = (const float*)d_in[5];
    const float* Wfc      = (const float*)d_in[6];
    const float* bfc      = (const float*)d_in[7];
    float* out = (float*)d_out;

    unsigned short* ws = (unsigned short*)d_ws;
    unsigned short* qbf  = ws;                 // 524288
    unsigned short* kbf  = qbf  + TOK * DH;    // 524288
    unsigned short* WqT  = kbf  + TOK * DH;    // 65536
    unsigned short* WkT  = WqT  + 64 * PROJC;
    unsigned short* WvT  = WkT  + 64 * PROJC;
    unsigned short* WfcT = WvT  + 64 * PROJC;  // 4096
    unsigned short* Qb   = WfcT + 64 * 64;     // 8388608 each
    unsigned short* Kb   = Qb   + (size_t)BSZ * NH * SEQ * DH;
    unsigned short* Vtb  = Kb   + (size_t)BSZ * NH * SEQ * DH;
    unsigned short* Ob   = Vtb  + (size_t)BSZ * NH * SEQ * DH;

    conv_kernel<<<dim3(2048, 2), 256, 0, stream>>>(q_origin, k_origin, qbf, kbf);
    wt_kernel<<<256, 256, 0, stream>>>(Wq, WqT, PROJC);
    wt_kernel<<<256, 256, 0, stream>>>(Wk, WkT, PROJC);
    wt_kernel<<<256, 256, 0, stream>>>(Wv, WvT, PROJC);
    wt_kernel<<<16, 256, 0, stream>>>(Wfc, WfcT, 64);
    proj_kernel<<<dim3(TOK / 64, PROJC / 64, 3), 256, 0, stream>>>(
        qbf, kbf, WqT, WkT, WvT, Qb, Kb, Vtb);
    attn_kernel<<<dim3(SEQ / 64, BSZ * NH), 256, 0, stream>>>(Qb, Kb, Vtb, mask, Ob);
    fc_kernel<<<(size_t)BSZ * SEQ * NH / 64, 256, 0, stream>>>(Ob, WfcT, bfc, out);
}